// Round 5
// baseline (108.687 us; speedup 1.0000x reference)
//
#include <hip/hip_runtime.h>

#define NPTS    8192
#define BATCH   2
#define CH      64
#define NGROUPS 50

#define TS      256                  // square tile side
#define NROW    (NPTS/TS)            // 32
#define NTILEB  (NROW*(NROW+1)/2)    // 528 triangle tiles per batch
#define MAINPB  (NTILEB*4)           // 2112 quarter-blocks per batch
#define MAINB   (BATCH*MAINPB)       // 4224
#define NBUCK   (BATCH*NGROUPS)      // 100
#define CORRB   (NBUCK*4)            // 400
#define GRID_T  (MAINB+CORRB)        // 4624
#define PAD     256                  // bucket capacity (7 sigma above mean 164)

// ------------- Kernel 1: Fsim (SoA + |f|^2) + per-label index compaction -------------
__global__ __launch_bounds__(256) void fsim_kernel(
    const float* __restrict__ l0, const float* __restrict__ W,
    const float* __restrict__ bias, const int* __restrict__ target,
    float* __restrict__ fx, float* __restrict__ fy, float* __restrict__ fz,
    float* __restrict__ fw, int* __restrict__ gidx, int* __restrict__ gcnt,
    int* __restrict__ counter)
{
    const int bid = blockIdx.x, tid = threadIdx.x;
    if (bid == 0 && tid == 0)
        __hip_atomic_store(counter, 0, __ATOMIC_RELAXED, __HIP_MEMORY_SCOPE_AGENT);

    if (bid < 256) {
        // ---- f computation: 64 points per block ----
        __shared__ float sW[3 * CH];
        if (tid < 3 * CH) sW[tid] = W[tid];
        __syncthreads();
        const int lane = tid & 63, wave = tid >> 6;
        const int p = lane & 15, cg = lane >> 4;
        const int pt = bid * 64 + wave * 16 + p;
        const int b = pt >> 13, n = pt & (NPTS - 1);
        const float* basep = l0 + (size_t)b * CH * NPTS + n;
        float ax = 0.f, ay = 0.f, az = 0.f;
        #pragma unroll
        for (int k = 0; k < 16; ++k) {
            int c = cg * 16 + k;
            float v = basep[(size_t)c * NPTS];
            ax = fmaf(sW[c], v, ax);
            ay = fmaf(sW[CH + c], v, ay);
            az = fmaf(sW[2*CH + c], v, az);
        }
        ax += __shfl_down(ax,32,64); ay += __shfl_down(ay,32,64); az += __shfl_down(az,32,64);
        ax += __shfl_down(ax,16,64); ay += __shfl_down(ay,16,64); az += __shfl_down(az,16,64);
        if (cg == 0) {
            float X = ax + bias[0], Y = ay + bias[1], Z = az + bias[2];
            fx[pt] = X; fy[pt] = Y; fz[pt] = Z;
            fw[pt] = fmaf(X, X, fmaf(Y, Y, Z * Z));
        }
    } else {
        // ---- index compaction for bucket (b, L); needs only `target` ----
        const int bucket = bid - 256;
        const int b = bucket / NGROUPS, L = bucket % NGROUPS;
        const int tbase = b * NPTS;
        __shared__ int scnt[256];
        int cnt = 0;
        const int4* t4 = (const int4*)&target[tbase];
        #pragma unroll
        for (int k8 = 0; k8 < 8; ++k8) {
            int4 tv = t4[tid * 8 + k8];
            cnt += (tv.x == L) + (tv.y == L) + (tv.z == L) + (tv.w == L);
        }
        scnt[tid] = cnt;
        __syncthreads();
        for (int s = 1; s < 256; s <<= 1) {       // Hillis-Steele inclusive scan
            int a = (tid >= s) ? scnt[tid - s] : 0;
            __syncthreads();
            scnt[tid] += a;
            __syncthreads();
        }
        int wpos = scnt[tid] - cnt;               // stable by point index
        for (int k = 0; k < 32; ++k) {
            int idx = tid * 32 + k;
            if (target[tbase + idx] == L) {
                if (wpos < PAD) gidx[bucket * PAD + wpos] = idx;
                ++wpos;
            }
        }
        if (tid == 0) gcnt[bucket] = min(scnt[255], PAD);
    }
}

// inner body: t = 1 + |fi|^2 + |fj|^2 - 2 fi.fj ; acc += 1/t^2
#define PAIR4(QX, QY, QZ, QP)                          \
    { _Pragma("unroll")                                \
      for (int u = 0; u < 4; ++u) {                    \
        float t = si[u] + (QP);                        \
        t = fmaf(nx[u], (QX), t);                      \
        t = fmaf(ny[u], (QY), t);                      \
        t = fmaf(nz[u], (QZ), t);                      \
        float r = __builtin_amdgcn_rcpf(t);            \
        acc[u] = fmaf(r, r, acc[u]);                   \
      } }

// ------------- Kernel 2: triangle rr-sum + bucket corrections + elected reduce -------------
__global__ __launch_bounds__(256) void mega_kernel(
    const float* __restrict__ fx, const float* __restrict__ fy,
    const float* __restrict__ fz, const float* __restrict__ fw,
    const int* __restrict__ gidx, const int* __restrict__ gcnt,
    double* __restrict__ partials, int* __restrict__ counter,
    float* __restrict__ out)
{
    const int bid = blockIdx.x, tid = threadIdx.x;
    __shared__ float4 sx[16], sy[16], sz[16], sp[16];
    __shared__ float4 pts[PAD];
    __shared__ double wsum[4];
    __shared__ int elect;

    float  accv = 0.0f;
    double cadd = 0.0;

    if (bid < MAINB) {
        // ---- uniform triangle quarter-block: 256 i's x 64 j's ----
        const int b   = bid / MAINPB;
        const int r   = bid % MAINPB;
        const int tau = r >> 2, q = r & 3;
        int it = (int)(32.5f - sqrtf(32.5f * 32.5f - 2.0f * (float)tau));
        if (it < 0) it = 0; if (it > NROW - 1) it = NROW - 1;
        while ((it + 1) * (65 - (it + 1)) / 2 <= tau) ++it;   // cum(r)=r*(65-r)/2
        while (it * (65 - it) / 2 > tau) --it;
        const int jt = it + (tau - it * (65 - it) / 2);

        const int base = b * NPTS;
        const int ib = base + it * TS + (tid & 63) * 4;
        const float4 vx = *(const float4*)&fx[ib];
        const float4 vy = *(const float4*)&fy[ib];
        const float4 vz = *(const float4*)&fz[ib];
        const float4 vw = *(const float4*)&fw[ib];
        const float nx[4] = {-2.f*vx.x, -2.f*vx.y, -2.f*vx.z, -2.f*vx.w};
        const float ny[4] = {-2.f*vy.x, -2.f*vy.y, -2.f*vy.z, -2.f*vy.w};
        const float nz[4] = {-2.f*vz.x, -2.f*vz.y, -2.f*vz.z, -2.f*vz.w};
        const float si[4] = {vw.x+1.f, vw.y+1.f, vw.z+1.f, vw.w+1.f};

        if (tid < 16) {
            const int a = base + jt * TS + q * 64 + 4 * tid;
            sx[tid] = *(const float4*)&fx[a];
            sy[tid] = *(const float4*)&fy[a];
            sz[tid] = *(const float4*)&fz[a];
            sp[tid] = *(const float4*)&fw[a];
        }
        __syncthreads();

        const int jg = (tid >> 6) * 4;     // this wave's 16-j slice (wave-uniform)
        float acc[4] = {0.f, 0.f, 0.f, 0.f};
        #pragma unroll
        for (int k = 0; k < 4; ++k) {
            float4 X = sx[jg+k], Y = sy[jg+k], Z = sz[jg+k], P = sp[jg+k];
            PAIR4(X.x, Y.x, Z.x, P.x)
            PAIR4(X.y, Y.y, Z.y, P.y)
            PAIR4(X.z, Y.z, Z.z, P.z)
            PAIR4(X.w, Y.w, Z.w, P.w)
        }
        float s = (acc[0] + acc[1]) + (acc[2] + acc[3]);
        accv = (it == jt) ? (2.0f * s) : (4.0f * s);   // 2R assembly
        if (it == jt && tid == 0) cadd = -128.0;       // 2*(S_q - 64) diag removal
    } else {
        // ---- bucket correction: ordered same-label pairs, (t - 2rr), masked ----
        const int cb = bid - MAINB;
        const int bucket = cb >> 2, sub = cb & 3;
        const int b = bucket / NGROUPS;
        const int cnt = gcnt[bucket];
        const int base = b * NPTS;
        {
            float4 pv = make_float4(0.f, 0.f, 0.f, 0.f);
            if (tid < cnt) {
                int ix = base + gidx[bucket * PAD + tid];
                pv = make_float4(fx[ix], fy[ix], fz[ix], 1.0f);
            }
            pts[tid] = pv;
        }
        __syncthreads();
        const int pp = sub * 64 + (tid & 63);
        const int g0 = (tid >> 6) * 64;
        if (pp < cnt) {
            const float4 a = pts[pp];
            float accB = 0.f;
            #pragma unroll 4
            for (int qq = g0; qq < g0 + 64; ++qq) {
                float4 c = pts[qq];
                float dx = a.x - c.x, dy = a.y - c.y, dz = a.z - c.z;
                float t = fmaf(dx, dx, fmaf(dy, dy, fmaf(dz, dz, 1.0f)));
                float rr = __builtin_amdgcn_rcpf(t); rr = rr * rr;
                accB = fmaf(fmaf(-2.0f, rr, t), c.w, accB);   // mask via c.w
            }
            accv = accB;
        }
        if (sub == 0 && tid == 0) {
            double c = (double)cnt;
            cadd = 2.0 * c - c * c;    // Sum_{p!=q}(d-2rr) = Sum_all(t-2rr) - c^2 + 2c
        }
    }

    // ---- combined block reduction ----
    #pragma unroll
    for (int o = 32; o > 0; o >>= 1) accv += __shfl_down(accv, o, 64);
    if ((tid & 63) == 0) wsum[tid >> 6] = (double)accv;
    __syncthreads();
    if (tid == 0) {
        partials[bid] = (wsum[0] + wsum[1]) + (wsum[2] + wsum[3]) + cadd;
        __threadfence();
        int old = atomicAdd(counter, 1);
        elect = (old == GRID_T - 1) ? 1 : 0;
    }
    __syncthreads();
    if (!elect) return;
    __threadfence();

    // elected (last) block: deterministic final reduction
    double ssum = 0.0;
    for (int k = tid; k < GRID_T; k += 256) {
        unsigned long long uv = __hip_atomic_load(
            (unsigned long long*)&partials[k], __ATOMIC_RELAXED, __HIP_MEMORY_SCOPE_AGENT);
        ssum += __longlong_as_double(uv);
    }
    #pragma unroll
    for (int o = 32; o > 0; o >>= 1) ssum += __shfl_down(ssum, o, 64);
    __shared__ double sd[4];
    if ((tid & 63) == 0) sd[tid >> 6] = ssum;
    __syncthreads();
    if (tid == 0) {
        double tot = (sd[0] + sd[1]) + (sd[2] + sd[3]);
        // total = 2*Sum_{i!=j} rr + bucket corrections (all folded in partials)
        out[0] = (float)(100.0 * tot / ((double)BATCH * NPTS * NPTS));
    }
}

extern "C" void kernel_launch(void* const* d_in, const int* in_sizes, int n_in,
                              void* d_out, int out_size, void* d_ws, size_t ws_size,
                              hipStream_t stream) {
    const float* l0     = (const float*)d_in[0];   // [2,64,8192]
    const float* W      = (const float*)d_in[1];   // [3,64]
    const float* bias   = (const float*)d_in[2];   // [3]
    const int*   target = (const int*)d_in[3];     // [2,8192]
    float* out = (float*)d_out;

    float* fx = (float*)d_ws;                      // 16384 floats each
    float* fy = fx + BATCH * NPTS;
    float* fz = fy + BATCH * NPTS;
    float* fw = fz + BATCH * NPTS;
    double* partials = (double*)((char*)d_ws + 4 * BATCH * NPTS * sizeof(float));
    int* gidx    = (int*)((char*)partials + GRID_T * sizeof(double));
    int* gcnt    = gidx + NBUCK * PAD;
    int* counter = gcnt + NBUCK;

    fsim_kernel<<<256 + NBUCK, 256, 0, stream>>>(l0, W, bias, target,
                                                 fx, fy, fz, fw, gidx, gcnt, counter);
    mega_kernel<<<GRID_T, 256, 0, stream>>>(fx, fy, fz, fw, gidx, gcnt,
                                            partials, counter, out);
}

// Round 6
// 33.102 us; speedup vs baseline: 3.2834x; 3.2834x over previous
//
#include <hip/hip_runtime.h>

#define NPTS    8192
#define BATCH   2
#define CH      64
#define NGROUPS 50

#define TS      256                  // square tile side
#define NROW    (NPTS/TS)            // 32
#define NTILEB  (NROW*(NROW+1)/2)    // 528 triangle tiles per batch
#define MAINPB  (NTILEB*2)           // 1056 half-tiles (256i x 128j) per batch
#define MAINB   (BATCH*MAINPB)       // 2112
#define NBUCK   (BATCH*NGROUPS)      // 100
#define CORRB   (NBUCK*4)            // 400 correction blocks (dispatched FIRST)
#define GRID_T  (CORRB+MAINB)        // 2512
#define PAD     256                  // bucket capacity

// ------------- Kernel 1: Fsim (SoA + |f|^2) + per-label index compaction -------------
__global__ __launch_bounds__(256) void fsim_kernel(
    const float* __restrict__ l0, const float* __restrict__ W,
    const float* __restrict__ bias, const int* __restrict__ target,
    float* __restrict__ fx, float* __restrict__ fy, float* __restrict__ fz,
    float* __restrict__ fw, int* __restrict__ gidx, int* __restrict__ gcnt)
{
    const int bid = blockIdx.x, tid = threadIdx.x;

    if (bid < 256) {
        // ---- f computation: 64 points per block ----
        __shared__ float sW[3 * CH];
        if (tid < 3 * CH) sW[tid] = W[tid];
        __syncthreads();
        const int lane = tid & 63, wave = tid >> 6;
        const int p = lane & 15, cg = lane >> 4;
        const int pt = bid * 64 + wave * 16 + p;
        const int b = pt >> 13, n = pt & (NPTS - 1);
        const float* basep = l0 + (size_t)b * CH * NPTS + n;
        float ax = 0.f, ay = 0.f, az = 0.f;
        #pragma unroll
        for (int k = 0; k < 16; ++k) {
            int c = cg * 16 + k;
            float v = basep[(size_t)c * NPTS];
            ax = fmaf(sW[c], v, ax);
            ay = fmaf(sW[CH + c], v, ay);
            az = fmaf(sW[2*CH + c], v, az);
        }
        ax += __shfl_down(ax,32,64); ay += __shfl_down(ay,32,64); az += __shfl_down(az,32,64);
        ax += __shfl_down(ax,16,64); ay += __shfl_down(ay,16,64); az += __shfl_down(az,16,64);
        if (cg == 0) {
            float X = ax + bias[0], Y = ay + bias[1], Z = az + bias[2];
            fx[pt] = X; fy[pt] = Y; fz[pt] = Z;
            fw[pt] = fmaf(X, X, fmaf(Y, Y, Z * Z));
        }
    } else {
        // ---- index compaction for bucket (b, L) ----
        const int bucket = bid - 256;
        const int b = bucket / NGROUPS, L = bucket % NGROUPS;
        const int tbase = b * NPTS;
        __shared__ int scnt[256];
        int cnt = 0;
        const int4* t4 = (const int4*)&target[tbase];
        #pragma unroll
        for (int k8 = 0; k8 < 8; ++k8) {
            int4 tv = t4[tid * 8 + k8];
            cnt += (tv.x == L) + (tv.y == L) + (tv.z == L) + (tv.w == L);
        }
        scnt[tid] = cnt;
        __syncthreads();
        for (int s = 1; s < 256; s <<= 1) {       // Hillis-Steele inclusive scan
            int a = (tid >= s) ? scnt[tid - s] : 0;
            __syncthreads();
            scnt[tid] += a;
            __syncthreads();
        }
        int wpos = scnt[tid] - cnt;               // stable by point index
        for (int k = 0; k < 32; ++k) {
            int idx = tid * 32 + k;
            if (target[tbase + idx] == L) {
                if (wpos < PAD) gidx[bucket * PAD + wpos] = idx;
                ++wpos;
            }
        }
        if (tid == 0) gcnt[bucket] = min(scnt[255], PAD);
    }
}

// inner body: t = 1 + |fi|^2 + |fj|^2 - 2 fi.fj ; acc += 1/t^2
#define PAIR4(QX, QY, QZ, QP)                          \
    { _Pragma("unroll")                                \
      for (int u = 0; u < 4; ++u) {                    \
        float t = si[u] + (QP);                        \
        t = fmaf(nx[u], (QX), t);                      \
        t = fmaf(ny[u], (QY), t);                      \
        t = fmaf(nz[u], (QZ), t);                      \
        float r = __builtin_amdgcn_rcpf(t);            \
        acc[u] = fmaf(r, r, acc[u]);                   \
      } }

// ------------- Kernel 2: triangle rr-sum (uniform) + bucket corrections -------------
// NO fences, NO atomics: each block writes one double to partials[bid].
__global__ __launch_bounds__(256) void pair_kernel(
    const float* __restrict__ fx, const float* __restrict__ fy,
    const float* __restrict__ fz, const float* __restrict__ fw,
    const int* __restrict__ gidx, const int* __restrict__ gcnt,
    double* __restrict__ partials)
{
    const int bid = blockIdx.x, tid = threadIdx.x;
    __shared__ float4 sj[PAD];      // main: 128 j-points; corr: 256 bucket points
    __shared__ double wsum[4];

    float  accv = 0.0f;
    double cadd = 0.0;

    if (bid >= CORRB) {
        // ---- uniform half-tile: 256 i's x 128 j's = 32K pairs ----
        const int mid = bid - CORRB;
        const int b   = mid / MAINPB;
        const int r   = mid % MAINPB;
        const int tau = r >> 1, half = r & 1;
        int ti = (int)(32.5f - sqrtf(32.5f * 32.5f - 2.0f * (float)tau));
        if (ti < 0) ti = 0; if (ti > NROW - 1) ti = NROW - 1;
        while ((ti + 1) * (65 - (ti + 1)) / 2 <= tau) ++ti;   // cum(r)=r*(65-r)/2
        while (ti * (65 - ti) / 2 > tau) --ti;
        const int tj = ti + (tau - ti * (65 - ti) / 2);

        const int base = b * NPTS;
        const int ib = base + ti * TS + (tid & 63) * 4;
        const float4 vx = *(const float4*)&fx[ib];
        const float4 vy = *(const float4*)&fy[ib];
        const float4 vz = *(const float4*)&fz[ib];
        const float4 vw = *(const float4*)&fw[ib];
        const float nx[4] = {-2.f*vx.x, -2.f*vx.y, -2.f*vx.z, -2.f*vx.w};
        const float ny[4] = {-2.f*vy.x, -2.f*vy.y, -2.f*vy.z, -2.f*vy.w};
        const float nz[4] = {-2.f*vz.x, -2.f*vz.y, -2.f*vz.z, -2.f*vz.w};
        const float si[4] = {vw.x+1.f, vw.y+1.f, vw.z+1.f, vw.w+1.f};

        if (tid < 128) {
            const int k = base + tj * TS + half * 128 + tid;
            sj[tid] = make_float4(fx[k], fy[k], fz[k], fw[k]);
        }
        __syncthreads();

        const int j0 = (tid >> 6) * 32;     // this wave's 32-j slice
        float acc[4] = {0.f, 0.f, 0.f, 0.f};
        #pragma unroll 4
        for (int jj = 0; jj < 32; ++jj) {
            float4 q = sj[j0 + jj];         // broadcast ds_read_b128
            PAIR4(q.x, q.y, q.z, q.w)
        }
        float s = (acc[0] + acc[1]) + (acc[2] + acc[3]);
        // weights reconstruct 2 * S_all(rr over full matrix incl diag)
        accv = (ti == tj) ? (2.0f * s) : (4.0f * s);
    } else {
        // ---- bucket correction: ordered same-label pairs, (t - 2rr), masked ----
        const int bucket = bid >> 2, sub = bid & 3;
        const int b = bucket / NGROUPS;
        const int cnt = gcnt[bucket];
        const int base = b * NPTS;
        {
            float4 pv = make_float4(0.f, 0.f, 0.f, 0.f);
            if (tid < cnt) {
                int ix = base + gidx[bucket * PAD + tid];
                pv = make_float4(fx[ix], fy[ix], fz[ix], 1.0f);
            }
            sj[tid] = pv;
        }
        __syncthreads();
        const int pp = sub * 64 + (tid & 63);
        const int g0 = (tid >> 6) * 64;
        if (pp < cnt) {
            const float4 a = sj[pp];
            float accB = 0.f;
            #pragma unroll 4
            for (int qq = g0; qq < g0 + 64; ++qq) {
                float4 c = sj[qq];
                float dx = a.x - c.x, dy = a.y - c.y, dz = a.z - c.z;
                float t = fmaf(dx, dx, fmaf(dy, dy, fmaf(dz, dz, 1.0f)));
                float rr = __builtin_amdgcn_rcpf(t); rr = rr * rr;
                accB = fmaf(fmaf(-2.0f, rr, t), c.w, accB);   // mask via c.w
            }
            accv = accB;
        }
        if (sub == 0 && tid == 0) {
            double c = (double)cnt;
            cadd = 2.0 * c - c * c;    // Sum_{p!=q}(d-2rr) = Sum_all(t-2rr) - c^2 + 2c
        }
    }

    // ---- block reduction -> one double, plain store ----
    #pragma unroll
    for (int o = 32; o > 0; o >>= 1) accv += __shfl_down(accv, o, 64);
    if ((tid & 63) == 0) wsum[tid >> 6] = (double)accv;
    __syncthreads();
    if (tid == 0)
        partials[bid] = (wsum[0] + wsum[1]) + (wsum[2] + wsum[3]) + cadd;
}

// ------------- Kernel 3: final reduce + scale -------------
__global__ __launch_bounds__(256) void finalize_kernel(
    const double* __restrict__ partials, float* __restrict__ out)
{
    const int tid = threadIdx.x;
    double s = 0.0;
    for (int k = tid; k < GRID_T; k += 256) s += partials[k];
    #pragma unroll
    for (int o = 32; o > 0; o >>= 1) s += __shfl_down(s, o, 64);
    __shared__ double sd[4];
    if ((tid & 63) == 0) sd[tid >> 6] = s;
    __syncthreads();
    if (tid == 0) {
        double tot = (sd[0] + sd[1]) + (sd[2] + sd[3]);
        // Sum(partials) = 2*S_all(rr) + corrections; remove 2*diag (rr(0)=1 each)
        tot -= 2.0 * (double)(BATCH * NPTS);
        out[0] = (float)(100.0 * tot / ((double)BATCH * NPTS * NPTS));
    }
}

extern "C" void kernel_launch(void* const* d_in, const int* in_sizes, int n_in,
                              void* d_out, int out_size, void* d_ws, size_t ws_size,
                              hipStream_t stream) {
    const float* l0     = (const float*)d_in[0];   // [2,64,8192]
    const float* W      = (const float*)d_in[1];   // [3,64]
    const float* bias   = (const float*)d_in[2];   // [3]
    const int*   target = (const int*)d_in[3];     // [2,8192]
    float* out = (float*)d_out;

    float* fx = (float*)d_ws;                      // 16384 floats each
    float* fy = fx + BATCH * NPTS;
    float* fz = fy + BATCH * NPTS;
    float* fw = fz + BATCH * NPTS;
    double* partials = (double*)((char*)d_ws + 4 * BATCH * NPTS * sizeof(float));
    int* gidx = (int*)((char*)partials + GRID_T * sizeof(double));
    int* gcnt = gidx + NBUCK * PAD;

    fsim_kernel<<<256 + NBUCK, 256, 0, stream>>>(l0, W, bias, target,
                                                 fx, fy, fz, fw, gidx, gcnt);
    pair_kernel<<<GRID_T, 256, 0, stream>>>(fx, fy, fz, fw, gidx, gcnt, partials);
    finalize_kernel<<<1, 256, 0, stream>>>(partials, out);
}

// Round 7
// 32.156 us; speedup vs baseline: 3.3800x; 1.0294x over previous
//
#include <hip/hip_runtime.h>

#define NPTS    8192
#define BATCH   2
#define CH      64
#define NGROUPS 50

#define TS      256                  // square tile side
#define NROW    (NPTS/TS)            // 32
#define NTILEB  (NROW*(NROW+1)/2)    // 528 triangle tiles per batch
#define MAINPB  (NTILEB*2)           // 1056 half-tiles (256i x 128j) per batch
#define MAINB   (BATCH*MAINPB)       // 2112
#define NBUCK   (BATCH*NGROUPS)      // 100
#define CORRB   (NBUCK*4)            // 400 correction blocks (dispatched FIRST)
#define GRID_T  (CORRB+MAINB)        // 2512
#define PAD     256                  // bucket capacity

typedef float v2f __attribute__((ext_vector_type(2)));
typedef float v4f __attribute__((ext_vector_type(4)));

// ------------- Kernel 1: Fsim (SoA + |f|^2) + per-label index compaction -------------
__global__ __launch_bounds__(256) void fsim_kernel(
    const float* __restrict__ l0, const float* __restrict__ W,
    const float* __restrict__ bias, const int* __restrict__ target,
    float* __restrict__ fx, float* __restrict__ fy, float* __restrict__ fz,
    float* __restrict__ fw, int* __restrict__ gidx, int* __restrict__ gcnt)
{
    const int bid = blockIdx.x, tid = threadIdx.x;

    if (bid < 256) {
        __shared__ float sW[3 * CH];
        if (tid < 3 * CH) sW[tid] = W[tid];
        __syncthreads();
        const int lane = tid & 63, wave = tid >> 6;
        const int p = lane & 15, cg = lane >> 4;
        const int pt = bid * 64 + wave * 16 + p;
        const int b = pt >> 13, n = pt & (NPTS - 1);
        const float* basep = l0 + (size_t)b * CH * NPTS + n;
        float ax = 0.f, ay = 0.f, az = 0.f;
        #pragma unroll
        for (int k = 0; k < 16; ++k) {
            int c = cg * 16 + k;
            float v = basep[(size_t)c * NPTS];
            ax = fmaf(sW[c], v, ax);
            ay = fmaf(sW[CH + c], v, ay);
            az = fmaf(sW[2*CH + c], v, az);
        }
        ax += __shfl_down(ax,32,64); ay += __shfl_down(ay,32,64); az += __shfl_down(az,32,64);
        ax += __shfl_down(ax,16,64); ay += __shfl_down(ay,16,64); az += __shfl_down(az,16,64);
        if (cg == 0) {
            float X = ax + bias[0], Y = ay + bias[1], Z = az + bias[2];
            fx[pt] = X; fy[pt] = Y; fz[pt] = Z;
            fw[pt] = fmaf(X, X, fmaf(Y, Y, Z * Z));
        }
    } else {
        const int bucket = bid - 256;
        const int b = bucket / NGROUPS, L = bucket % NGROUPS;
        const int tbase = b * NPTS;
        __shared__ int scnt[256];
        int cnt = 0;
        const int4* t4 = (const int4*)&target[tbase];
        #pragma unroll
        for (int k8 = 0; k8 < 8; ++k8) {
            int4 tv = t4[tid * 8 + k8];
            cnt += (tv.x == L) + (tv.y == L) + (tv.z == L) + (tv.w == L);
        }
        scnt[tid] = cnt;
        __syncthreads();
        for (int s = 1; s < 256; s <<= 1) {       // Hillis-Steele inclusive scan
            int a = (tid >= s) ? scnt[tid - s] : 0;
            __syncthreads();
            scnt[tid] += a;
            __syncthreads();
        }
        int wpos = scnt[tid] - cnt;               // stable by point index
        for (int k = 0; k < 32; ++k) {
            int idx = tid * 32 + k;
            if (target[tbase + idx] == L) {
                if (wpos < PAD) gidx[bucket * PAD + wpos] = idx;
                ++wpos;
            }
        }
        if (tid == 0) gcnt[bucket] = min(scnt[255], PAD);
    }
}

// packed inner body over an i-pair: t = si + wj - 2 fi.fj + 1 ; acc += rcp(t)^2
#define PKPAIR(NX, NY, NZ, SI, ACC)                                  \
    {                                                                \
        v2f t = SI + qww;                                            \
        t = __builtin_elementwise_fma(NX, qxx, t);                   \
        t = __builtin_elementwise_fma(NY, qyy, t);                   \
        t = __builtin_elementwise_fma(NZ, qzz, t);                   \
        v2f r;                                                       \
        r.x = __builtin_amdgcn_rcpf(t.x);                            \
        r.y = __builtin_amdgcn_rcpf(t.y);                            \
        ACC = __builtin_elementwise_fma(r, r, ACC);                  \
    }

// ------------- Kernel 2: triangle rr-sum (uniform) + bucket corrections -------------
__global__ __launch_bounds__(256) void pair_kernel(
    const float* __restrict__ fx, const float* __restrict__ fy,
    const float* __restrict__ fz, const float* __restrict__ fw,
    const int* __restrict__ gidx, const int* __restrict__ gcnt,
    double* __restrict__ partials)
{
    const int bid = blockIdx.x, tid = threadIdx.x;
    __shared__ float4 sj[PAD];      // main: 128 j-points duplicated (2 float4 each); corr: 256 pts
    __shared__ double wsum[4];

    float  accv = 0.0f;
    double cadd = 0.0;

    if (bid >= CORRB) {
        // ---- uniform half-tile: 256 i's x 128 j's = 32K pairs ----
        const int mid = bid - CORRB;
        const int b   = mid / MAINPB;
        const int r   = mid % MAINPB;
        const int tau = r >> 1, half = r & 1;
        int ti = (int)(32.5f - sqrtf(32.5f * 32.5f - 2.0f * (float)tau));
        if (ti < 0) ti = 0; if (ti > NROW - 1) ti = NROW - 1;
        while ((ti + 1) * (65 - (ti + 1)) / 2 <= tau) ++ti;   // cum(r)=r*(65-r)/2
        while (ti * (65 - ti) / 2 > tau) --ti;
        const int tj = ti + (tau - ti * (65 - ti) / 2);

        const int base = b * NPTS;
        const int ib = base + ti * TS + (tid & 63) * 4;
        const float4 vx = *(const float4*)&fx[ib];
        const float4 vy = *(const float4*)&fy[ib];
        const float4 vz = *(const float4*)&fz[ib];
        const float4 vw = *(const float4*)&fw[ib];
        const v2f nx01 = {-2.f*vx.x, -2.f*vx.y}, nx23 = {-2.f*vx.z, -2.f*vx.w};
        const v2f ny01 = {-2.f*vy.x, -2.f*vy.y}, ny23 = {-2.f*vy.z, -2.f*vy.w};
        const v2f nz01 = {-2.f*vz.x, -2.f*vz.y}, nz23 = {-2.f*vz.z, -2.f*vz.w};
        const v2f si01 = {vw.x+1.f, vw.y+1.f},   si23 = {vw.z+1.f, vw.w+1.f};

        if (tid < 128) {
            const int k = base + tj * TS + half * 128 + tid;
            const float X = fx[k], Y = fy[k], Z = fz[k], Wq = fw[k];
            sj[2*tid]   = make_float4(X, X, Y, Y);   // duplicated for packed ops
            sj[2*tid+1] = make_float4(Z, Z, Wq, Wq);
        }
        __syncthreads();

        const int j0 = (tid >> 6) * 32;     // this wave's 32-j slice
        v2f acc01 = {0.f, 0.f}, acc23 = {0.f, 0.f};
        const v4f* sj4 = (const v4f*)sj;
        #pragma unroll 4
        for (int jj = 0; jj < 32; ++jj) {
            const v4f A = sj4[2*(j0+jj)];       // {x,x,y,y}
            const v4f B = sj4[2*(j0+jj)+1];     // {z,z,w,w}
            const v2f qxx = A.xy, qyy = A.zw, qzz = B.xy, qww = B.zw;
            PKPAIR(nx01, ny01, nz01, si01, acc01)
            PKPAIR(nx23, ny23, nz23, si23, acc23)
        }
        float s = (acc01.x + acc01.y) + (acc23.x + acc23.y);
        // weights reconstruct 2 * S_all(rr over full matrix incl diag)
        accv = (ti == tj) ? (2.0f * s) : (4.0f * s);
    } else {
        // ---- bucket correction: ordered same-label pairs, (t - 2rr), masked ----
        const int bucket = bid >> 2, sub = bid & 3;
        const int b = bucket / NGROUPS;
        const int cnt = gcnt[bucket];
        const int base = b * NPTS;
        {
            float4 pv = make_float4(0.f, 0.f, 0.f, 0.f);
            if (tid < cnt) {
                int ix = base + gidx[bucket * PAD + tid];
                pv = make_float4(fx[ix], fy[ix], fz[ix], 1.0f);
            }
            sj[tid] = pv;
        }
        __syncthreads();
        const int pp = sub * 64 + (tid & 63);
        const int g0 = (tid >> 6) * 64;
        if (pp < cnt) {
            const float4 a = sj[pp];
            float accB = 0.f;
            #pragma unroll 4
            for (int qq = g0; qq < g0 + 64; ++qq) {
                float4 c = sj[qq];
                float dx = a.x - c.x, dy = a.y - c.y, dz = a.z - c.z;
                float t = fmaf(dx, dx, fmaf(dy, dy, fmaf(dz, dz, 1.0f)));
                float rr = __builtin_amdgcn_rcpf(t); rr = rr * rr;
                accB = fmaf(fmaf(-2.0f, rr, t), c.w, accB);   // mask via c.w
            }
            accv = accB;
        }
        if (sub == 0 && tid == 0) {
            double c = (double)cnt;
            cadd = 2.0 * c - c * c;    // Sum_{p!=q}(d-2rr) = Sum_all(t-2rr) - c^2 + 2c
        }
    }

    // ---- block reduction -> one double, plain store ----
    #pragma unroll
    for (int o = 32; o > 0; o >>= 1) accv += __shfl_down(accv, o, 64);
    if ((tid & 63) == 0) wsum[tid >> 6] = (double)accv;
    __syncthreads();
    if (tid == 0)
        partials[bid] = (wsum[0] + wsum[1]) + (wsum[2] + wsum[3]) + cadd;
}

// ------------- Kernel 3: final reduce + scale -------------
__global__ __launch_bounds__(256) void finalize_kernel(
    const double* __restrict__ partials, float* __restrict__ out)
{
    const int tid = threadIdx.x;
    double s = 0.0;
    for (int k = tid; k < GRID_T; k += 256) s += partials[k];
    #pragma unroll
    for (int o = 32; o > 0; o >>= 1) s += __shfl_down(s, o, 64);
    __shared__ double sd[4];
    if ((tid & 63) == 0) sd[tid >> 6] = s;
    __syncthreads();
    if (tid == 0) {
        double tot = (sd[0] + sd[1]) + (sd[2] + sd[3]);
        // Sum(partials) = 2*S_all(rr) + corrections; remove 2*diag (rr(0)=1 each)
        tot -= 2.0 * (double)(BATCH * NPTS);
        out[0] = (float)(100.0 * tot / ((double)BATCH * NPTS * NPTS));
    }
}

extern "C" void kernel_launch(void* const* d_in, const int* in_sizes, int n_in,
                              void* d_out, int out_size, void* d_ws, size_t ws_size,
                              hipStream_t stream) {
    const float* l0     = (const float*)d_in[0];   // [2,64,8192]
    const float* W      = (const float*)d_in[1];   // [3,64]
    const float* bias   = (const float*)d_in[2];   // [3]
    const int*   target = (const int*)d_in[3];     // [2,8192]
    float* out = (float*)d_out;

    float* fx = (float*)d_ws;                      // 16384 floats each
    float* fy = fx + BATCH * NPTS;
    float* fz = fy + BATCH * NPTS;
    float* fw = fz + BATCH * NPTS;
    double* partials = (double*)((char*)d_ws + 4 * BATCH * NPTS * sizeof(float));
    int* gidx = (int*)((char*)partials + GRID_T * sizeof(double));
    int* gcnt = gidx + NBUCK * PAD;

    fsim_kernel<<<256 + NBUCK, 256, 0, stream>>>(l0, W, bias, target,
                                                 fx, fy, fz, fw, gidx, gcnt);
    pair_kernel<<<GRID_T, 256, 0, stream>>>(fx, fy, fz, fw, gidx, gcnt, partials);
    finalize_kernel<<<1, 256, 0, stream>>>(partials, out);
}